// Round 1
// baseline (376.564 us; speedup 1.0000x reference)
//
#include <hip/hip_runtime.h>
#include <cstdint>

// Problem: M=16384, K=2048, N=2048 fp8(e4m3) delayed-scaling dense fwd.
#define M_DIM 16384
#define K_DIM 2048
#define N_DIM 2048

typedef float f32x4 __attribute__((ext_vector_type(4)));
typedef int   i32x8 __attribute__((ext_vector_type(8)));

// ---------------------------------------------------------------------------
// Kernel 1: quantize x [M,K] f32 -> fp8 e4m3 (RNE via v_cvt_pk_fp8_f32),
// fused amax. Grid-stride float4 loads: 64 lanes x 16B consecutive = 1KB/instr.
// ---------------------------------------------------------------------------
__global__ __launch_bounds__(256) void quant_x_kernel(
    const float4* __restrict__ x, uint4* __restrict__ xq,
    const float* __restrict__ scale, unsigned int* __restrict__ amax)
{
    const int gid = blockIdx.x * 256 + threadIdx.x;   // 4096*256 = 1048576 threads
    const float s = scale[0];
    float m = 0.0f;
#pragma unroll
    for (int j = 0; j < 8; ++j) {
        float4 v = x[gid + j * 1048576];
        m = fmaxf(m, fmaxf(fmaxf(fabsf(v.x), fabsf(v.y)),
                           fmaxf(fabsf(v.z), fabsf(v.w))));
        unsigned int p0 = __builtin_amdgcn_cvt_pk_fp8_f32(v.x * s, v.y * s, 0, false);
        unsigned int p  = __builtin_amdgcn_cvt_pk_fp8_f32(v.z * s, v.w * s, p0, true);
        ((unsigned int*)xq)[gid + j * 1048576] = p;   // 4 fp8 per dword, coalesced
    }

#pragma unroll
    for (int off = 32; off > 0; off >>= 1)
        m = fmaxf(m, __shfl_down(m, off, 64));
    __shared__ float red[4];
    if ((threadIdx.x & 63) == 0) red[threadIdx.x >> 6] = m;
    __syncthreads();
    if (threadIdx.x == 0) {
        m = fmaxf(fmaxf(red[0], red[1]), fmaxf(red[2], red[3]));
        atomicMax(amax, __float_as_uint(m));  // values >= 0: uint order == float order
    }
}

// ---------------------------------------------------------------------------
// Kernel 2: quantize + transpose kernel [K,N] f32 -> wq [N,K] fp8, fused amax.
// ---------------------------------------------------------------------------
__global__ __launch_bounds__(256) void quant_w_kernel(
    const float* __restrict__ w, uint8_t* __restrict__ wq,
    const float* __restrict__ scale, unsigned int* __restrict__ amax)
{
    __shared__ float tile[64][68];
    const int t = threadIdx.x;
    const int nb = blockIdx.x * 64;
    const int kb = blockIdx.y * 64;
    const float s = scale[1];
    float m = 0.0f;
#pragma unroll
    for (int j = 0; j < 4; ++j) {
        int f = j * 256 + t;
        int row = f >> 4;
        int c4 = f & 15;
        float4 v = *(const float4*)(w + (size_t)(kb + row) * N_DIM + nb + c4 * 4);
        m = fmaxf(m, fmaxf(fmaxf(fabsf(v.x), fabsf(v.y)),
                           fmaxf(fabsf(v.z), fabsf(v.w))));
        *(float4*)(&tile[row][c4 * 4]) = v;
    }
    __syncthreads();
    const int n = t >> 2, c = t & 3;
    unsigned int pk[4];
#pragma unroll
    for (int jj = 0; jj < 4; ++jj) {
        float f0 = tile[c * 16 + jj * 4 + 0][n] * s;
        float f1 = tile[c * 16 + jj * 4 + 1][n] * s;
        float f2 = tile[c * 16 + jj * 4 + 2][n] * s;
        float f3 = tile[c * 16 + jj * 4 + 3][n] * s;
        unsigned int p = __builtin_amdgcn_cvt_pk_fp8_f32(f0, f1, 0, false);
        pk[jj] = __builtin_amdgcn_cvt_pk_fp8_f32(f2, f3, p, true);
    }
    *(uint4*)(wq + (size_t)(nb + n) * K_DIM + kb + c * 16) = make_uint4(pk[0], pk[1], pk[2], pk[3]);

#pragma unroll
    for (int off = 32; off > 0; off >>= 1)
        m = fmaxf(m, __shfl_down(m, off, 64));
    __shared__ float red[4];
    if ((t & 63) == 0) red[t >> 6] = m;
    __syncthreads();
    if (t == 0) {
        m = fmaxf(fmaxf(red[0], red[1]), fmaxf(red[2], red[3]));
        atomicMax(amax, __float_as_uint(m));
    }
}

// ---------------------------------------------------------------------------
// Kernel 3: MX-scaled fp8 GEMM, 8-phase counted-vmcnt schedule (T2+T3+T4+T5).
//   C[m,n] = sum_k Aq[m,k]*Bq[n,k] via mfma_scale_f32_16x16x128_f8f6f4,
//   e8m0 scales = 1.0 (0x7F).
//
// Geometry: 256x256 tile, 512 threads = 8 waves (2M x 4N), 128x64 per wave,
// BK = 128 bytes (one mfma-K). K-steps: 2048/128 = 16, double-buffered.
// LDS: lA[2][32KB] + lB[2][32KB] = 128 KiB dynamic (opt-in attribute).
//
// LDS layout per buffer: 16 groups of 16 rows x 128B = 2KB/group.
// Fragment semantics (verified by previous passing kernel): lane l holds
// row (l&15), k-bytes (l>>4)*32 + [0..31] of its group.
// Granule swizzle (16B granules, n = 2*l + h, h = lo/hi b128):
//   n' = n ^ ((n>>3)&1)   -- involution; consecutive 8 lanes of each
// ds_read_b128 cover all 8 bank-quads -> conflict-free reads AND lane-linear
// 16B staging dst (global_load_lds requirement); the same involution is
// applied to the per-lane GLOBAL source address (rule 21: both-sides).
//
// Staging: 8 rounds/K-step (each = 512 thr x 16B = 8KB, wave w -> group
// table[w>>1], seg w&1). Round order R0..R7 = {A g0-3, A g8-11, B nh0,
// B nh0', B nh1, B nh1', A g4-7, A g12-15} chosen so a uniform
// s_waitcnt vmcnt(4) at phases 0,1,3 (never 0 in the loop) guarantees
// exactly the rounds the next phase's ds_reads consume (2 new rounds are
// issued per phase; oldest-first retirement does the rest). Last iteration
// wrap-stages kt=0 (harmless, keeps counts uniform).
// Per phase p: (mh,nh)=(p>>1,p&1); A frags held across the two nh-phases.
// ---------------------------------------------------------------------------
#define LDSBUF 32768

__global__ __launch_bounds__(512, 2) void gemm_fp8_kernel(
    const uint8_t* __restrict__ Aq, const uint8_t* __restrict__ Bq,
    const float* __restrict__ scale, float* __restrict__ C)
{
    extern __shared__ uint8_t lds[];
    uint8_t* const lA = lds;                  // [2][LDSBUF]
    uint8_t* const lB = lds + 2 * LDSBUF;     // [2][LDSBUF]

    const int tid  = threadIdx.x;
    const int wave = tid >> 6;
    const int lane = tid & 63;
    const int wm = wave >> 2, wn = wave & 3;  // 2(M) x 4(N) wave grid
    const int q = lane >> 4, r = lane & 15;

    const int bn = blockIdx.x;                // 0..7
    const int bm = blockIdx.y;                // 0..63

    // Read scales up front, then drain all counters so the K-loop's counted
    // vmcnt tracks ONLY the global_load_lds stream.
    const float s0 = scale[0];
    const float s1 = scale[1];
    asm volatile("s_waitcnt vmcnt(0) lgkmcnt(0)" ::: "memory");

    // ---- staging lane constants ----
    const int seg = wave & 1;                 // segment (half-group) per wave
    const int wp  = wave >> 1;                // 0..3
    const int gbB = wp + ((wp >> 1) << 1);    // {0,1,4,5}
    const int npr = seg * 64 + lane;          // staging granule within group
    const int nin = npr ^ ((npr >> 3) & 1);   // involution -> logical granule
    const int srow = (nin >> 1) & 15;                         // row in group
    const int skb  = (((nin >> 1) >> 4) << 5) + ((nin & 1) << 4); // k-byte
    const int sdst = seg * 1024 + lane * 16;  // lane-linear LDS dst in group

    const uint8_t* aS = Aq + (size_t)(bm * 256 + srow) * K_DIM + skb;
    const uint8_t* bS = Bq + (size_t)(bn * 256 + srow) * K_DIM + skb;

#define STAGE_A(buf, kb, g)                                                          \
    __builtin_amdgcn_global_load_lds(                                                \
        (const __attribute__((address_space(1))) uint32_t*)(aS + (size_t)(g) * (16 * K_DIM) + (kb)), \
        (__attribute__((address_space(3))) uint32_t*)(lA + (buf) * LDSBUF + (g) * 2048 + sdst), 16, 0, 0)
#define STAGE_B(buf, kb, g)                                                          \
    __builtin_amdgcn_global_load_lds(                                                \
        (const __attribute__((address_space(1))) uint32_t*)(bS + (size_t)(g) * (16 * K_DIM) + (kb)), \
        (__attribute__((address_space(3))) uint32_t*)(lB + (buf) * LDSBUF + (g) * 2048 + sdst), 16, 0, 0)

    // ---- fragment read offsets (swizzled, conflict-free) ----
    const int sb   = (lane >> 2) & 1;
    const int offL = (((lane << 1) ^ sb) << 4);
    const int offH = ((((lane << 1) + 1) ^ sb) << 4);

    f32x4 acc[8][4];
#pragma unroll
    for (int i = 0; i < 8; ++i)
#pragma unroll
        for (int j = 0; j < 4; ++j) acc[i][j] = (f32x4){0.f, 0.f, 0.f, 0.f};

    // ---- prologue: stage all 8 rounds of K-step 0 into buffer 0 ----
    STAGE_A(0, 0, wp);       STAGE_A(0, 0, 8 + wp);
    STAGE_B(0, 0, gbB);      STAGE_B(0, 0, 8 + gbB);
    STAGE_B(0, 0, 2 + gbB);  STAGE_B(0, 0, 10 + gbB);
    STAGE_A(0, 0, 4 + wp);   STAGE_A(0, 0, 12 + wp);
    asm volatile("s_waitcnt vmcnt(4)" ::: "memory");
    __builtin_amdgcn_s_barrier();

    const int SONE = 0x7F7F7F7F;   // e8m0 scale = 1.0 in every byte

#pragma unroll 2
    for (int t = 0; t < 16; ++t) {
        const int cur = t & 1, nxt = cur ^ 1;
        const int kbn = ((t + 1) & 15) * 128;     // wrap-stage on last iter
        uint8_t* const curA = lA + cur * LDSBUF;
        uint8_t* const curB = lB + cur * LDSBUF;
        i32x8 a_frag[4];
#pragma unroll
        for (int p = 0; p < 4; ++p) {
            const int mh = p >> 1, nh = p & 1;
            if (nh == 0) {                        // load A half, hold 2 phases
#pragma unroll
                for (int mi = 0; mi < 4; ++mi) {
                    const uint8_t* pa = curA + (wm * 8 + mh * 4 + mi) * 2048;
                    int4 lo = *(const int4*)(pa + offL);
                    int4 hi = *(const int4*)(pa + offH);
                    a_frag[mi] = (i32x8){lo.x, lo.y, lo.z, lo.w,
                                         hi.x, hi.y, hi.z, hi.w};
                }
            }
            i32x8 b_frag[2];
#pragma unroll
            for (int j = 0; j < 2; ++j) {
                const uint8_t* pb = curB + (wn * 4 + nh * 2 + j) * 2048;
                int4 lo = *(const int4*)(pb + offL);
                int4 hi = *(const int4*)(pb + offH);
                b_frag[j] = (i32x8){lo.x, lo.y, lo.z, lo.w,
                                    hi.x, hi.y, hi.z, hi.w};
            }
            // 2 staging rounds per phase into the other buffer
            if (p == 0)      { STAGE_A(nxt, kbn, wp);       STAGE_A(nxt, kbn, 8 + wp); }
            else if (p == 1) { STAGE_B(nxt, kbn, gbB);      STAGE_B(nxt, kbn, 8 + gbB); }
            else if (p == 2) { STAGE_B(nxt, kbn, 2 + gbB);  STAGE_B(nxt, kbn, 10 + gbB); }
            else             { STAGE_A(nxt, kbn, 4 + wp);   STAGE_A(nxt, kbn, 12 + wp); }

            if (p != 2) asm volatile("s_waitcnt vmcnt(4)" ::: "memory");
            __builtin_amdgcn_s_barrier();
            asm volatile("s_waitcnt lgkmcnt(0)" ::: "memory");
            __builtin_amdgcn_sched_barrier(0);
            __builtin_amdgcn_s_setprio(1);
#pragma unroll
            for (int mi = 0; mi < 4; ++mi)
#pragma unroll
                for (int j = 0; j < 2; ++j)
                    acc[mh * 4 + mi][nh * 2 + j] =
                        __builtin_amdgcn_mfma_scale_f32_16x16x128_f8f6f4(
                            a_frag[mi], b_frag[j], acc[mh * 4 + mi][nh * 2 + j],
                            0 /*cbsz: fp8*/, 0 /*blgp: fp8*/,
                            0, SONE, 0, SONE);
            __builtin_amdgcn_s_setprio(0);
            __builtin_amdgcn_s_barrier();
        }
    }
#undef STAGE_A
#undef STAGE_B

    // epilogue: D col = lane&15, row = q*4 + reg (m89-verified, shape-determined)
    const float sinv = (1.0f / s0) * (1.0f / s1);
#pragma unroll
    for (int mi = 0; mi < 8; ++mi) {
#pragma unroll
        for (int ni = 0; ni < 4; ++ni) {
            const int col  = bn * 256 + wn * 64 + ni * 16 + r;
            const int row0 = bm * 256 + wm * 128 + mi * 16 + q * 4;
#pragma unroll
            for (int rr = 0; rr < 4; ++rr)
                C[(size_t)(row0 + rr) * N_DIM + col] = acc[mi][ni][rr] * sinv;
        }
    }
}

// ---------------------------------------------------------------------------
// Kernel 4: scale update (faithful _sf_compute incl. tf.where ordering) +
// rolled amax history (always zeros for 1-row history).
// ---------------------------------------------------------------------------
__global__ void finalize_kernel(const float* __restrict__ scale,
                                const unsigned int* __restrict__ amax_bits,
                                float* __restrict__ out_tail)
{
    const int i = threadIdx.x;
    if (i < 2) {
        const float amax = __uint_as_float(amax_bits[i]);
        const float sc = scale[i];
        const float e = floorf(log2f(448.0f / amax));
        float sf = roundf(exp2f(fabsf(e)));
        sf = (amax > 0.0f) ? sf : sc;
        sf = isinf(amax) ? sf : sc;      // faithful: finite amax collapses to scale
        if (e < 0.0f) sf = 1.0f / sf;
        out_tail[i] = sf;                // new_scale
        out_tail[2 + i] = 0.0f;          // rolled history (single row -> zeros)
    }
}

// ---------------------------------------------------------------------------
extern "C" void kernel_launch(void* const* d_in, const int* in_sizes, int n_in,
                              void* d_out, int out_size, void* d_ws, size_t ws_size,
                              hipStream_t stream)
{
    const float* x     = (const float*)d_in[0];
    const float* w     = (const float*)d_in[1];
    const float* scale = (const float*)d_in[2];

    uint8_t* ws = (uint8_t*)d_ws;
    uint8_t* xq = ws;                                            // M*K fp8 (32 MB)
    uint8_t* wq = ws + (size_t)M_DIM * K_DIM;                    // N*K fp8 (4 MB)
    unsigned int* amax = (unsigned int*)(ws + (size_t)M_DIM * K_DIM + (size_t)N_DIM * K_DIM);

    static int lds_opt_in = 0;           // one-time 128 KiB dynamic-LDS opt-in
    if (!lds_opt_in) {
        hipFuncSetAttribute((const void*)gemm_fp8_kernel,
                            hipFuncAttributeMaxDynamicSharedMemorySize, 131072);
        lds_opt_in = 1;
    }

    hipMemsetAsync(amax, 0, 2 * sizeof(unsigned int), stream);

    quant_x_kernel<<<4096, 256, 0, stream>>>(
        (const float4*)x, (uint4*)xq, scale, amax);

    dim3 gw(N_DIM / 64, K_DIM / 64);
    quant_w_kernel<<<gw, 256, 0, stream>>>(w, wq, scale, amax + 1);

    dim3 gg(N_DIM / 256, M_DIM / 256);
    gemm_fp8_kernel<<<gg, 512, 131072, stream>>>(xq, wq, scale, (float*)d_out);

    finalize_kernel<<<1, 64, 0, stream>>>(scale, amax,
                                          (float*)d_out + (size_t)M_DIM * N_DIM);
}